// Round 3
// baseline (1091.352 us; speedup 1.0000x reference)
//
#include <hip/hip_runtime.h>

// Problem constants
constexpr int B  = 16;
constexpr int H  = 64;
constexpr int W  = 64;
constexpr int C  = 256;
constexpr int NH = 8;
constexpr int KD = 32;
constexpr float SCALE = 0.17677669529663687f; // 32^-0.5
constexpr int M_TOT = B * H * W;              // 65536
constexpr size_t NEL = (size_t)B * H * W * C; // 16777216

__device__ __forceinline__ unsigned short f2bf(float f) {
    union { float f; unsigned int u; } x; x.f = f;
    unsigned int u = x.u;
    unsigned int r = (u + 0x7fffu + ((u >> 16) & 1u)) >> 16;
    return (unsigned short)r;
}
__device__ __forceinline__ float bf_lo(unsigned int u) {
    union { unsigned int u; float f; } x; x.u = u << 16; return x.f;
}
__device__ __forceinline__ float bf_hi(unsigned int u) {
    union { unsigned int u; float f; } x; x.u = u & 0xffff0000u; return x.f;
}

// ---------------------------------------------------------------------------
// Kernel 1: fused QKV GEMM (+bias, k-scale, rotary theta_shift, layout xform)
// x:(M,256) @ W:(256,256). Tile 64x64, BK=16, 256 threads, 4x4 per thread.
// mat 0 -> qr (B,NH,H,W,KD) rotated, bf16
// mat 1 -> kr (B,NH,H,W,KD) scaled+rotated, bf16
// mat 2 -> v  (B,H,W,C) fp32
// ---------------------------------------------------------------------------
__global__ __launch_bounds__(256) void qkv_kernel(
    const float* __restrict__ x,
    const float* __restrict__ Wq, const float* __restrict__ bq,
    const float* __restrict__ Wk, const float* __restrict__ bk,
    const float* __restrict__ Wv, const float* __restrict__ bv,
    const float* __restrict__ sin_t, const float* __restrict__ cos_t,
    unsigned short* __restrict__ qr, unsigned short* __restrict__ kr,
    float* __restrict__ v)
{
    const int mat = blockIdx.y >> 2;   // 0=q 1=k 2=v
    const int nb  = blockIdx.y & 3;    // 64-col block
    const int mb  = blockIdx.x;        // 64-row block
    const float* __restrict__ Wt   = (mat == 0) ? Wq : ((mat == 1) ? Wk : Wv);
    const float* __restrict__ bias = (mat == 0) ? bq : ((mat == 1) ? bk : bv);

    __shared__ float As[16][65];  // As[k][m]
    __shared__ float Bs[16][65];  // Bs[k][n]

    const int t  = threadIdx.x;
    const int tr = t >> 4, tc = t & 15;
    const int m0 = mb * 64, n0 = nb * 64;

    float acc[4][4] = {};

    for (int k0 = 0; k0 < 256; k0 += 16) {
        {
            int row = t >> 2, c4 = (t & 3) << 2;
            float4 f = *(const float4*)(x + (size_t)(m0 + row) * 256 + k0 + c4);
            As[c4 + 0][row] = f.x; As[c4 + 1][row] = f.y;
            As[c4 + 2][row] = f.z; As[c4 + 3][row] = f.w;
        }
        {
            int row = t >> 4, c4 = (t & 15) << 2;
            float4 f = *(const float4*)(Wt + (size_t)(k0 + row) * 256 + n0 + c4);
            Bs[row][c4 + 0] = f.x; Bs[row][c4 + 1] = f.y;
            Bs[row][c4 + 2] = f.z; Bs[row][c4 + 3] = f.w;
        }
        __syncthreads();
#pragma unroll
        for (int k = 0; k < 16; ++k) {
            float a[4], bb[4];
#pragma unroll
            for (int i = 0; i < 4; ++i) a[i] = As[k][tr * 4 + i];
#pragma unroll
            for (int j = 0; j < 4; ++j) bb[j] = Bs[k][tc * 4 + j];
#pragma unroll
            for (int i = 0; i < 4; ++i)
#pragma unroll
                for (int j = 0; j < 4; ++j) acc[i][j] += a[i] * bb[j];
        }
        __syncthreads();
    }

    const int m_base = m0 + tr * 4;
    const int n_base = n0 + tc * 4;

    if (mat == 2) {
#pragma unroll
        for (int i = 0; i < 4; ++i)
#pragma unroll
            for (int j = 0; j < 4; ++j) {
                int m = m_base + i, n = n_base + j;
                v[(size_t)m * 256 + n] = acc[i][j] + bias[n];
            }
    } else {
        const float sc = (mat == 1) ? SCALE : 1.0f;
        unsigned int* __restrict__ dst = (unsigned int*)((mat == 0) ? qr : kr);
#pragma unroll
        for (int i = 0; i < 4; ++i) {
            int m = m_base + i;
            int bb2 = m >> 12, hh = (m >> 6) & 63, ww = m & 63;
            const float* cs = cos_t + ((size_t)hh * 64 + ww) * 32;
            const float* sn = sin_t + ((size_t)hh * 64 + ww) * 32;
#pragma unroll
            for (int j = 0; j < 4; j += 2) {
                int n = n_base + j;
                int nh = n >> 5, d = n & 31;
                float e = (acc[i][j]     + bias[n])     * sc;
                float o = (acc[i][j + 1] + bias[n + 1]) * sc;
                float re = e * cs[d]     - o * sn[d];
                float ro = o * cs[d + 1] + e * sn[d + 1];
                size_t idx = ((((size_t)bb2 * NH + nh) * H + hh) * W + ww) * KD + d;
                dst[idx >> 1] = (unsigned int)f2bf(re) | ((unsigned int)f2bf(ro) << 16);
            }
        }
    }
}

// ---------------------------------------------------------------------------
// Kernel 2: 5x5 depthwise conv (lepe), NHWC, zero-pad 2
// ---------------------------------------------------------------------------
__global__ __launch_bounds__(256) void conv_kernel(
    const float* __restrict__ v, const float* __restrict__ cw,
    const float* __restrict__ cb, float* __restrict__ lepe)
{
    size_t idx = (size_t)blockIdx.x * 256 + threadIdx.x;
    int c = idx & 255;
    int w = (idx >> 8) & 63;
    int h = (idx >> 14) & 63;
    int b = (int)(idx >> 20);
    float acc = cb[c];
#pragma unroll
    for (int dy = 0; dy < 5; ++dy) {
        int yy = h + dy - 2;
        if (yy < 0 || yy >= 64) continue;
#pragma unroll
        for (int dx = 0; dx < 5; ++dx) {
            int xx = w + dx - 2;
            if (xx < 0 || xx >= 64) continue;
            acc += v[(((size_t)(b * 64 + yy) * 64) + xx) * 256 + c] * cw[(dy * 5 + dx) * 256 + c];
        }
    }
    lepe[idx] = acc;
}

// ---------------------------------------------------------------------------
// Kernel 3/4: attention along one axis.
// AXIS=0: per (b, h, nh): S = qr(w,d) . kr(w',d)^T + mask_w; softmax; P @ v -> vv
// AXIS=1: per (b, w, nh): S = qr(h,d) . kr(h',d)^T + mask_h; softmax; P @ vv (+lepe) -> y
// qr/kr layout (B,NH,H,W,KD) bf16; v/vv/y layout (B,H,W,C) fp32
// ---------------------------------------------------------------------------
template <int AXIS>
__global__ __launch_bounds__(256) void attn_kernel(
    const unsigned short* __restrict__ qr, const unsigned short* __restrict__ kr,
    const float* __restrict__ vin, const float* __restrict__ mask,
    const float* __restrict__ addin, float* __restrict__ outp)
{
    __shared__ float qs[64][33], ks[64][33], vs[64][33];
    __shared__ float S[64][65];

    const int t   = threadIdx.x;
    const int bid = blockIdx.x;
    const int nh  = bid & 7;
    const int pos = (bid >> 3) & 63;   // h (AXIS=0) or w (AXIS=1)
    const int b   = bid >> 9;

    size_t qbase, vbase;
    int qstride, vstride;
    if (AXIS == 0) {
        qbase   = ((size_t)(b * 8 + nh) * 64 + pos) * 2048;
        qstride = 32;
        vbase   = ((size_t)(b * 64 + pos) * 64) * 256 + nh * 32;
        vstride = 256;
    } else {
        qbase   = ((size_t)(b * 8 + nh) * 64) * 2048 + pos * 32;
        qstride = 2048;
        vbase   = ((size_t)b * 64 * 64) * 256 + pos * 256 + nh * 32;
        vstride = 16384;
    }

    // load q,k (bf16, 8 elems = uint4 per thread covers 64 rows x 32)
    {
        int row = t >> 2, c8 = (t & 3) * 8;
        uint4 rq = *(const uint4*)(qr + qbase + (size_t)row * qstride + c8);
        qs[row][c8 + 0] = bf_lo(rq.x); qs[row][c8 + 1] = bf_hi(rq.x);
        qs[row][c8 + 2] = bf_lo(rq.y); qs[row][c8 + 3] = bf_hi(rq.y);
        qs[row][c8 + 4] = bf_lo(rq.z); qs[row][c8 + 5] = bf_hi(rq.z);
        qs[row][c8 + 6] = bf_lo(rq.w); qs[row][c8 + 7] = bf_hi(rq.w);
        uint4 rk = *(const uint4*)(kr + qbase + (size_t)row * qstride + c8);
        ks[row][c8 + 0] = bf_lo(rk.x); ks[row][c8 + 1] = bf_hi(rk.x);
        ks[row][c8 + 2] = bf_lo(rk.y); ks[row][c8 + 3] = bf_hi(rk.y);
        ks[row][c8 + 4] = bf_lo(rk.z); ks[row][c8 + 5] = bf_hi(rk.z);
        ks[row][c8 + 6] = bf_lo(rk.w); ks[row][c8 + 7] = bf_hi(rk.w);
    }
    // load v (fp32)
#pragma unroll
    for (int i = 0; i < 2; ++i) {
        int idx = t + i * 256;            // 0..511
        int row = idx >> 3, c4 = (idx & 7) << 2;
        float4 fv = *(const float4*)(vin + vbase + (size_t)row * vstride + c4);
        vs[row][c4] = fv.x; vs[row][c4 + 1] = fv.y; vs[row][c4 + 2] = fv.z; vs[row][c4 + 3] = fv.w;
    }
    __syncthreads();

    // S = q . k^T + mask
    {
        const int tr = t >> 4, tc = t & 15;
        const float* __restrict__ mrow = mask + (size_t)nh * 4096;
        float acc[4][4] = {};
#pragma unroll
        for (int d = 0; d < 32; ++d) {
            float a[4], bb[4];
#pragma unroll
            for (int i = 0; i < 4; ++i) a[i] = qs[tr * 4 + i][d];
#pragma unroll
            for (int j = 0; j < 4; ++j) bb[j] = ks[tc * 4 + j][d];
#pragma unroll
            for (int i = 0; i < 4; ++i)
#pragma unroll
                for (int j = 0; j < 4; ++j) acc[i][j] += a[i] * bb[j];
        }
#pragma unroll
        for (int i = 0; i < 4; ++i)
#pragma unroll
            for (int j = 0; j < 4; ++j) {
                int r = tr * 4 + i, c = tc * 4 + j;
                S[r][c] = acc[i][j] + mrow[r * 64 + c];
            }
    }
    __syncthreads();

    // row softmax: 4 lanes per row, 16 cols each
    {
        int r = t >> 2, c0 = (t & 3) * 16;
        float mx = -1e30f;
#pragma unroll
        for (int j = 0; j < 16; ++j) mx = fmaxf(mx, S[r][c0 + j]);
        mx = fmaxf(mx, __shfl_xor(mx, 1));
        mx = fmaxf(mx, __shfl_xor(mx, 2));
        float sum = 0.f;
        float ev[16];
#pragma unroll
        for (int j = 0; j < 16; ++j) { float e = __expf(S[r][c0 + j] - mx); ev[j] = e; sum += e; }
        sum += __shfl_xor(sum, 1);
        sum += __shfl_xor(sum, 2);
        float inv = 1.0f / sum;
#pragma unroll
        for (int j = 0; j < 16; ++j) S[r][c0 + j] = ev[j] * inv;
    }
    __syncthreads();

    // out = P @ V  (64x64 @ 64x32); thread: row r, 8 d-cols
    {
        int r = t >> 2, d0 = (t & 3) * 8;
        float o[8] = {};
#pragma unroll 8
        for (int k = 0; k < 64; ++k) {
            float pv = S[r][k];
#pragma unroll
            for (int j = 0; j < 8; ++j) o[j] += pv * vs[k][d0 + j];
        }
        size_t oidx = vbase + (size_t)r * vstride + d0;
        if (AXIS == 0) {
#pragma unroll
            for (int j = 0; j < 8; ++j) outp[oidx + j] = o[j];
        } else {
#pragma unroll
            for (int j = 0; j < 8; ++j) outp[oidx + j] = addin[oidx + j] + o[j];
        }
    }
}

// ---------------------------------------------------------------------------
// Kernel 5: output GEMM y(M,256) @ Wo(256,256) + bo -> out
// ---------------------------------------------------------------------------
__global__ __launch_bounds__(256) void gemm_out_kernel(
    const float* __restrict__ y, const float* __restrict__ Wo,
    const float* __restrict__ bo, float* __restrict__ out)
{
    const int nb = blockIdx.y;
    const int mb = blockIdx.x;

    __shared__ float As[16][65];
    __shared__ float Bs[16][65];

    const int t  = threadIdx.x;
    const int tr = t >> 4, tc = t & 15;
    const int m0 = mb * 64, n0 = nb * 64;

    float acc[4][4] = {};

    for (int k0 = 0; k0 < 256; k0 += 16) {
        {
            int row = t >> 2, c4 = (t & 3) << 2;
            float4 f = *(const float4*)(y + (size_t)(m0 + row) * 256 + k0 + c4);
            As[c4 + 0][row] = f.x; As[c4 + 1][row] = f.y;
            As[c4 + 2][row] = f.z; As[c4 + 3][row] = f.w;
        }
        {
            int row = t >> 4, c4 = (t & 15) << 2;
            float4 f = *(const float4*)(Wo + (size_t)(k0 + row) * 256 + n0 + c4);
            Bs[row][c4 + 0] = f.x; Bs[row][c4 + 1] = f.y;
            Bs[row][c4 + 2] = f.z; Bs[row][c4 + 3] = f.w;
        }
        __syncthreads();
#pragma unroll
        for (int k = 0; k < 16; ++k) {
            float a[4], bb[4];
#pragma unroll
            for (int i = 0; i < 4; ++i) a[i] = As[k][tr * 4 + i];
#pragma unroll
            for (int j = 0; j < 4; ++j) bb[j] = Bs[k][tc * 4 + j];
#pragma unroll
            for (int i = 0; i < 4; ++i)
#pragma unroll
                for (int j = 0; j < 4; ++j) acc[i][j] += a[i] * bb[j];
        }
        __syncthreads();
    }

#pragma unroll
    for (int i = 0; i < 4; ++i)
#pragma unroll
        for (int j = 0; j < 4; ++j) {
            int m = m0 + tr * 4 + i, n = n0 + tc * 4 + j;
            out[(size_t)m * 256 + n] = acc[i][j] + bo[n];
        }
}

// ---------------------------------------------------------------------------
extern "C" void kernel_launch(void* const* d_in, const int* in_sizes, int n_in,
                              void* d_out, int out_size, void* d_ws, size_t ws_size,
                              hipStream_t stream) {
    const float* x      = (const float*)d_in[0];
    const float* sin_t  = (const float*)d_in[1];
    const float* cos_t  = (const float*)d_in[2];
    const float* mask_h = (const float*)d_in[3];
    const float* mask_w = (const float*)d_in[4];
    const float* Wq     = (const float*)d_in[5];
    const float* bq     = (const float*)d_in[6];
    const float* Wk     = (const float*)d_in[7];
    const float* bk     = (const float*)d_in[8];
    const float* Wv     = (const float*)d_in[9];
    const float* bv     = (const float*)d_in[10];
    const float* conv_w = (const float*)d_in[11];
    const float* conv_b = (const float*)d_in[12];
    const float* Wo     = (const float*)d_in[13];
    const float* bo     = (const float*)d_in[14];

    // workspace layout (192 MiB total):
    //   v    : NEL fp32 (64 MiB)   -- reused as y after attn-W
    //   lepe : NEL fp32 (64 MiB)
    //   qr16 : NEL bf16 (32 MiB)
    //   kr16 : NEL bf16 (32 MiB)
    // vv lives in d_out (scratch until final GEMM overwrites it)
    float* ws   = (float*)d_ws;
    float* v    = ws;
    float* lepe = ws + NEL;
    unsigned short* qr16 = (unsigned short*)(ws + 2 * NEL);
    unsigned short* kr16 = qr16 + NEL;
    float* vv   = (float*)d_out;
    float* y    = v;  // reuse

    // 1. QKV GEMM + rotary
    qkv_kernel<<<dim3(M_TOT / 64, 12), 256, 0, stream>>>(
        x, Wq, bq, Wk, bk, Wv, bv, sin_t, cos_t, qr16, kr16, v);

    // 2. depthwise conv -> lepe
    conv_kernel<<<(int)(NEL / 256), 256, 0, stream>>>(v, conv_w, conv_b, lepe);

    // 3. W-axis attention -> vv (in d_out)
    attn_kernel<0><<<B * H * NH, 256, 0, stream>>>(qr16, kr16, v, mask_w, nullptr, vv);

    // 4. H-axis attention + lepe -> y (reuses v buffer)
    attn_kernel<1><<<B * W * NH, 256, 0, stream>>>(qr16, kr16, vv, mask_h, lepe, y);

    // 5. output GEMM
    gemm_out_kernel<<<dim3(M_TOT / 64, 4), 256, 0, stream>>>(y, Wo, bo, (float*)d_out);
}

// Round 4
// 604.089 us; speedup vs baseline: 1.8066x; 1.8066x over previous
//
#include <hip/hip_runtime.h>

typedef __attribute__((ext_vector_type(8))) short bf16x8;
typedef __attribute__((ext_vector_type(4))) float f32x4;

constexpr int B  = 16;
constexpr int H  = 64;
constexpr int W  = 64;
constexpr int C  = 256;
constexpr int NH = 8;
constexpr int KD = 32;
constexpr float SCALE = 0.17677669529663687f; // 32^-0.5
constexpr int M_TOT = B * H * W;              // 65536
constexpr size_t NEL = (size_t)B * H * W * C; // 16777216

__device__ __forceinline__ unsigned short f2bf(float f) {
    union { float f; unsigned int u; } x; x.f = f;
    unsigned int u = x.u;
    unsigned int r = (u + 0x7fffu + ((u >> 16) & 1u)) >> 16;
    return (unsigned short)r;
}
__device__ __forceinline__ float bf2f(unsigned short s) {
    union { unsigned int u; float f; } x; x.u = ((unsigned int)s) << 16; return x.f;
}
__device__ __forceinline__ float bf_lo(unsigned int u) {
    union { unsigned int u; float f; } x; x.u = u << 16; return x.f;
}
__device__ __forceinline__ float bf_hi(unsigned int u) {
    union { unsigned int u; float f; } x; x.u = u & 0xffff0000u; return x.f;
}
__device__ __forceinline__ unsigned int pack2(float a, float b) {
    return (unsigned int)f2bf(a) | ((unsigned int)f2bf(b) << 16);
}
// LDS chunk swizzle: row of 32 bf16 (64B) split into 4 16B chunks; XOR chunk id
// with bits 2-3 of row so ds_read_b128 column reads land on distinct bank pairs.
__device__ __forceinline__ int swz(int row, int kp8) {
    return row * 32 + (kp8 ^ (((row >> 2) & 3) << 3));
}

// ---------------------------------------------------------------------------
// prep: x fp32 -> bf16
// ---------------------------------------------------------------------------
__global__ __launch_bounds__(256) void prep_x16(const float* __restrict__ x,
                                                unsigned short* __restrict__ x16) {
    size_t i8 = ((size_t)blockIdx.x * 256 + threadIdx.x) * 8;
    float4 f0 = *(const float4*)(x + i8);
    float4 f1 = *(const float4*)(x + i8 + 4);
    uint4 o;
    o.x = pack2(f0.x, f0.y); o.y = pack2(f0.z, f0.w);
    o.z = pack2(f1.x, f1.y); o.w = pack2(f1.z, f1.w);
    *(uint4*)(x16 + i8) = o;
}

// ---------------------------------------------------------------------------
// prep: W (256k x 256n fp32, row-major k) -> Wt16[n][k] bf16 (n-major)
// 32 blocks x 256 threads; thread -> (n, 8 k's)
// ---------------------------------------------------------------------------
__global__ __launch_bounds__(256) void trans_w(const float* __restrict__ src,
                                               unsigned short* __restrict__ dst) {
    int tid = blockIdx.x * 256 + threadIdx.x;   // 0..8191
    int n = tid >> 5, k0 = (tid & 31) << 3;
    unsigned int p[4];
#pragma unroll
    for (int j = 0; j < 4; ++j) {
        float a  = src[(size_t)(k0 + 2 * j) * 256 + n];
        float b2 = src[(size_t)(k0 + 2 * j + 1) * 256 + n];
        p[j] = pack2(a, b2);
    }
    uint4 o = {p[0], p[1], p[2], p[3]};
    *(uint4*)(dst + (size_t)n * 256 + k0) = o;
}

// ---------------------------------------------------------------------------
// Kernel 1: fused QKV MFMA GEMM. x16(M,256)bf16 @ Wt16(768,256)^T.
// 128x128 tile, BK=32, 4 waves (each 64x64 = 4x4 16x16 frags).
// blockIdx.y 0..5: matid = y>>1 (0=q,1=k,2=v).
// q/k epilogue: +bias, (k: *SCALE), rotary via shfl_xor(1), -> (B,NH,H,W,KD) bf16
// v epilogue: +bias -> (B,H,W,C) bf16
// ---------------------------------------------------------------------------
__global__ __launch_bounds__(256) void qkv_mfma(
    const unsigned short* __restrict__ x16, const unsigned short* __restrict__ Wt16,
    const float* __restrict__ bq, const float* __restrict__ bk, const float* __restrict__ bv,
    const float* __restrict__ sin_t, const float* __restrict__ cos_t,
    unsigned short* __restrict__ qr, unsigned short* __restrict__ kr,
    unsigned short* __restrict__ v16)
{
    __shared__ __align__(16) short As[128 * 32];
    __shared__ __align__(16) short Bs[128 * 32];

    const int t = threadIdx.x;
    const int lane = t & 63, wid = t >> 6;
    const int wr = wid >> 1, wc = wid & 1;
    const int m0 = blockIdx.x * 128;
    const int n0 = blockIdx.y * 128;
    const int matid = blockIdx.y >> 1;

    f32x4 acc[4][4];
#pragma unroll
    for (int i = 0; i < 4; ++i)
#pragma unroll
        for (int j = 0; j < 4; ++j)
#pragma unroll
            for (int q = 0; q < 4; ++q) acc[i][j][q] = 0.f;

    const int row_s = t >> 2;            // 0..63
    const int kp_s  = (t & 3) << 3;      // 0,8,16,24

    for (int ks = 0; ks < 8; ++ks) {
        const int k0 = ks * 32;
        const unsigned short* ap = x16 + (size_t)(m0 + row_s) * 256 + k0 + kp_s;
        uint4 a0 = *(const uint4*)ap;
        uint4 a1 = *(const uint4*)(ap + 64 * 256);
        const unsigned short* bp = Wt16 + (size_t)(n0 + row_s) * 256 + k0 + kp_s;
        uint4 b0 = *(const uint4*)bp;
        uint4 b1 = *(const uint4*)(bp + 64 * 256);

        __syncthreads();   // previous iteration's ds_reads complete
        *(uint4*)(&As[swz(row_s,      kp_s)]) = a0;
        *(uint4*)(&As[swz(row_s + 64, kp_s)]) = a1;
        *(uint4*)(&Bs[swz(row_s,      kp_s)]) = b0;
        *(uint4*)(&Bs[swz(row_s + 64, kp_s)]) = b1;
        __syncthreads();   // tile ready

        bf16x8 af[4], bf[4];
        const int rsel = lane & 15, kg8 = (lane >> 4) << 3;
#pragma unroll
        for (int i = 0; i < 4; ++i)
            af[i] = *(const bf16x8*)(&As[swz(wr * 64 + i * 16 + rsel, kg8)]);
#pragma unroll
        for (int j = 0; j < 4; ++j)
            bf[j] = *(const bf16x8*)(&Bs[swz(wc * 64 + j * 16 + rsel, kg8)]);
#pragma unroll
        for (int i = 0; i < 4; ++i)
#pragma unroll
            for (int j = 0; j < 4; ++j)
                acc[i][j] = __builtin_amdgcn_mfma_f32_16x16x32_bf16(af[i], bf[j], acc[i][j], 0, 0, 0);
    }

    // epilogue. C frag: col = lane&15, row = (lane>>4)*4 + r
    const int col_l = lane & 15, rowg = (lane >> 4) << 2;
    if (matid == 2) {
#pragma unroll
        for (int i = 0; i < 4; ++i)
#pragma unroll
            for (int j = 0; j < 4; ++j) {
                int nn = (n0 & 255) + wc * 64 + j * 16 + col_l;
                float bias = bv[nn];
#pragma unroll
                for (int r = 0; r < 4; ++r) {
                    int m = m0 + wr * 64 + i * 16 + rowg + r;
                    v16[(size_t)m * 256 + nn] = f2bf(acc[i][j][r] + bias);
                }
            }
    } else {
        const float sc = matid ? SCALE : 1.0f;
        const float* __restrict__ bias = matid ? bk : bq;
        unsigned short* __restrict__ dst = matid ? kr : qr;
        const int par = lane & 1;
#pragma unroll
        for (int i = 0; i < 4; ++i)
#pragma unroll
            for (int j = 0; j < 4; ++j) {
                int nn = (n0 & 255) + wc * 64 + j * 16 + col_l;
                int nh = nn >> 5, d = nn & 31;
                float bs = bias[nn];
#pragma unroll
                for (int r = 0; r < 4; ++r) {
                    int m = m0 + wr * 64 + i * 16 + rowg + r;
                    float val = (acc[i][j][r] + bs) * sc;
                    float p = __shfl_xor(val, 1);
                    int bb = m >> 12, hh = (m >> 6) & 63, ww = m & 63;
                    size_t ti = ((size_t)(hh << 6) + ww) * 32 + d;
                    float cs = cos_t[ti], sn = sin_t[ti];
                    float ov = par ? (val * cs + p * sn) : (val * cs - p * sn);
                    dst[((((size_t)bb * 8 + nh) * 64 + hh) * 64 + ww) * 32 + d] = f2bf(ov);
                }
            }
    }
}

// ---------------------------------------------------------------------------
// Kernel 2: 5x5 depthwise conv (lepe), NHWC bf16 in/out, fp32 weights
// ---------------------------------------------------------------------------
__global__ __launch_bounds__(256) void conv_kernel(
    const unsigned short* __restrict__ v, const float* __restrict__ cw,
    const float* __restrict__ cb, unsigned short* __restrict__ lepe)
{
    size_t idx = (size_t)blockIdx.x * 256 + threadIdx.x;
    int c = idx & 255;
    int w = (idx >> 8) & 63;
    int h = (idx >> 14) & 63;
    int b = (int)(idx >> 20);
    float acc = cb[c];
#pragma unroll
    for (int dy = 0; dy < 5; ++dy) {
        int yy = h + dy - 2;
        if (yy < 0 || yy >= 64) continue;
#pragma unroll
        for (int dx = 0; dx < 5; ++dx) {
            int xx = w + dx - 2;
            if (xx < 0 || xx >= 64) continue;
            acc += bf2f(v[(((size_t)(b * 64 + yy) * 64) + xx) * 256 + c]) * cw[(dy * 5 + dx) * 256 + c];
        }
    }
    lepe[idx] = f2bf(acc);
}

// ---------------------------------------------------------------------------
// Kernel 3/4: attention along one axis (all tensor I/O bf16, math fp32)
// ---------------------------------------------------------------------------
template <int AXIS>
__global__ __launch_bounds__(256) void attn_kernel(
    const unsigned short* __restrict__ qr, const unsigned short* __restrict__ kr,
    const unsigned short* __restrict__ vin, const float* __restrict__ mask,
    const unsigned short* __restrict__ addin, unsigned short* __restrict__ outp)
{
    __shared__ float qs[64][33], ks[64][33], vs[64][33];
    __shared__ float S[64][65];

    const int t   = threadIdx.x;
    const int bid = blockIdx.x;
    const int nh  = bid & 7;
    const int pos = (bid >> 3) & 63;
    const int b   = bid >> 9;

    size_t qbase, vbase;
    int qstride, vstride;
    if (AXIS == 0) {
        qbase   = ((size_t)(b * 8 + nh) * 64 + pos) * 2048;
        qstride = 32;
        vbase   = ((size_t)(b * 64 + pos) * 64) * 256 + nh * 32;
        vstride = 256;
    } else {
        qbase   = ((size_t)(b * 8 + nh) * 64) * 2048 + pos * 32;
        qstride = 2048;
        vbase   = ((size_t)b * 64 * 64) * 256 + pos * 256 + nh * 32;
        vstride = 16384;
    }

    {
        int row = t >> 2, c8 = (t & 3) * 8;
        uint4 rq = *(const uint4*)(qr + qbase + (size_t)row * qstride + c8);
        qs[row][c8 + 0] = bf_lo(rq.x); qs[row][c8 + 1] = bf_hi(rq.x);
        qs[row][c8 + 2] = bf_lo(rq.y); qs[row][c8 + 3] = bf_hi(rq.y);
        qs[row][c8 + 4] = bf_lo(rq.z); qs[row][c8 + 5] = bf_hi(rq.z);
        qs[row][c8 + 6] = bf_lo(rq.w); qs[row][c8 + 7] = bf_hi(rq.w);
        uint4 rk = *(const uint4*)(kr + qbase + (size_t)row * qstride + c8);
        ks[row][c8 + 0] = bf_lo(rk.x); ks[row][c8 + 1] = bf_hi(rk.x);
        ks[row][c8 + 2] = bf_lo(rk.y); ks[row][c8 + 3] = bf_hi(rk.y);
        ks[row][c8 + 4] = bf_lo(rk.z); ks[row][c8 + 5] = bf_hi(rk.z);
        ks[row][c8 + 6] = bf_lo(rk.w); ks[row][c8 + 7] = bf_hi(rk.w);
        uint4 rv = *(const uint4*)(vin + vbase + (size_t)row * vstride + c8);
        vs[row][c8 + 0] = bf_lo(rv.x); vs[row][c8 + 1] = bf_hi(rv.x);
        vs[row][c8 + 2] = bf_lo(rv.y); vs[row][c8 + 3] = bf_hi(rv.y);
        vs[row][c8 + 4] = bf_lo(rv.z); vs[row][c8 + 5] = bf_hi(rv.z);
        vs[row][c8 + 6] = bf_lo(rv.w); vs[row][c8 + 7] = bf_hi(rv.w);
    }
    __syncthreads();

    {
        const int tr = t >> 4, tc = t & 15;
        const float* __restrict__ mrow = mask + (size_t)nh * 4096;
        float acc[4][4] = {};
#pragma unroll
        for (int d = 0; d < 32; ++d) {
            float a[4], bb[4];
#pragma unroll
            for (int i = 0; i < 4; ++i) a[i] = qs[tr * 4 + i][d];
#pragma unroll
            for (int j = 0; j < 4; ++j) bb[j] = ks[tc * 4 + j][d];
#pragma unroll
            for (int i = 0; i < 4; ++i)
#pragma unroll
                for (int j = 0; j < 4; ++j) acc[i][j] += a[i] * bb[j];
        }
#pragma unroll
        for (int i = 0; i < 4; ++i)
#pragma unroll
            for (int j = 0; j < 4; ++j) {
                int r = tr * 4 + i, c = tc * 4 + j;
                S[r][c] = acc[i][j] + mrow[r * 64 + c];
            }
    }
    __syncthreads();

    {
        int r = t >> 2, c0 = (t & 3) * 16;
        float mx = -1e30f;
#pragma unroll
        for (int j = 0; j < 16; ++j) mx = fmaxf(mx, S[r][c0 + j]);
        mx = fmaxf(mx, __shfl_xor(mx, 1));
        mx = fmaxf(mx, __shfl_xor(mx, 2));
        float sum = 0.f;
        float ev[16];
#pragma unroll
        for (int j = 0; j < 16; ++j) { float e = __expf(S[r][c0 + j] - mx); ev[j] = e; sum += e; }
        sum += __shfl_xor(sum, 1);
        sum += __shfl_xor(sum, 2);
        float inv = 1.0f / sum;
#pragma unroll
        for (int j = 0; j < 16; ++j) S[r][c0 + j] = ev[j] * inv;
    }
    __syncthreads();

    {
        int r = t >> 2, d0 = (t & 3) * 8;
        float o[8] = {};
#pragma unroll 8
        for (int k = 0; k < 64; ++k) {
            float pv = S[r][k];
#pragma unroll
            for (int j = 0; j < 8; ++j) o[j] += pv * vs[k][d0 + j];
        }
        size_t oidx = vbase + (size_t)r * vstride + d0;
        if (AXIS == 1) {
            uint4 lv = *(const uint4*)(addin + oidx);
            o[0] += bf_lo(lv.x); o[1] += bf_hi(lv.x);
            o[2] += bf_lo(lv.y); o[3] += bf_hi(lv.y);
            o[4] += bf_lo(lv.z); o[5] += bf_hi(lv.z);
            o[6] += bf_lo(lv.w); o[7] += bf_hi(lv.w);
        }
        uint4 ov;
        ov.x = pack2(o[0], o[1]); ov.y = pack2(o[2], o[3]);
        ov.z = pack2(o[4], o[5]); ov.w = pack2(o[6], o[7]);
        *(uint4*)(outp + oidx) = ov;
    }
}

// ---------------------------------------------------------------------------
// Kernel 5: output MFMA GEMM: y16(M,256)bf16 @ Wot16(256,256)^T + bo -> fp32
// ---------------------------------------------------------------------------
__global__ __launch_bounds__(256) void gemm_out_mfma(
    const unsigned short* __restrict__ y16, const unsigned short* __restrict__ Wot16,
    const float* __restrict__ bo, float* __restrict__ out)
{
    __shared__ __align__(16) short As[128 * 32];
    __shared__ __align__(16) short Bs[128 * 32];

    const int t = threadIdx.x;
    const int lane = t & 63, wid = t >> 6;
    const int wr = wid >> 1, wc = wid & 1;
    const int m0 = blockIdx.x * 128;
    const int n0 = blockIdx.y * 128;

    f32x4 acc[4][4];
#pragma unroll
    for (int i = 0; i < 4; ++i)
#pragma unroll
        for (int j = 0; j < 4; ++j)
#pragma unroll
            for (int q = 0; q < 4; ++q) acc[i][j][q] = 0.f;

    const int row_s = t >> 2;
    const int kp_s  = (t & 3) << 3;

    for (int ks = 0; ks < 8; ++ks) {
        const int k0 = ks * 32;
        const unsigned short* ap = y16 + (size_t)(m0 + row_s) * 256 + k0 + kp_s;
        uint4 a0 = *(const uint4*)ap;
        uint4 a1 = *(const uint4*)(ap + 64 * 256);
        const unsigned short* bp = Wot16 + (size_t)(n0 + row_s) * 256 + k0 + kp_s;
        uint4 b0 = *(const uint4*)bp;
        uint4 b1 = *(const uint4*)(bp + 64 * 256);

        __syncthreads();
        *(uint4*)(&As[swz(row_s,      kp_s)]) = a0;
        *(uint4*)(&As[swz(row_s + 64, kp_s)]) = a1;
        *(uint4*)(&Bs[swz(row_s,      kp_s)]) = b0;
        *(uint4*)(&Bs[swz(row_s + 64, kp_s)]) = b1;
        __syncthreads();

        bf16x8 af[4], bf[4];
        const int rsel = lane & 15, kg8 = (lane >> 4) << 3;
#pragma unroll
        for (int i = 0; i < 4; ++i)
            af[i] = *(const bf16x8*)(&As[swz(wr * 64 + i * 16 + rsel, kg8)]);
#pragma unroll
        for (int j = 0; j < 4; ++j)
            bf[j] = *(const bf16x8*)(&Bs[swz(wc * 64 + j * 16 + rsel, kg8)]);
#pragma unroll
        for (int i = 0; i < 4; ++i)
#pragma unroll
            for (int j = 0; j < 4; ++j)
                acc[i][j] = __builtin_amdgcn_mfma_f32_16x16x32_bf16(af[i], bf[j], acc[i][j], 0, 0, 0);
    }

    const int col_l = lane & 15, rowg = (lane >> 4) << 2;
#pragma unroll
    for (int i = 0; i < 4; ++i)
#pragma unroll
        for (int j = 0; j < 4; ++j) {
            int nn = n0 + wc * 64 + j * 16 + col_l;
            float bias = bo[nn];
#pragma unroll
            for (int r = 0; r < 4; ++r) {
                int m = m0 + wr * 64 + i * 16 + rowg + r;
                out[(size_t)m * 256 + nn] = acc[i][j][r] + bias;
            }
        }
}

// ---------------------------------------------------------------------------
extern "C" void kernel_launch(void* const* d_in, const int* in_sizes, int n_in,
                              void* d_out, int out_size, void* d_ws, size_t ws_size,
                              hipStream_t stream) {
    const float* x      = (const float*)d_in[0];
    const float* sin_t  = (const float*)d_in[1];
    const float* cos_t  = (const float*)d_in[2];
    const float* mask_h = (const float*)d_in[3];
    const float* mask_w = (const float*)d_in[4];
    const float* Wq     = (const float*)d_in[5];
    const float* bq     = (const float*)d_in[6];
    const float* Wk     = (const float*)d_in[7];
    const float* bk     = (const float*)d_in[8];
    const float* Wv     = (const float*)d_in[9];
    const float* bv     = (const float*)d_in[10];
    const float* conv_w = (const float*)d_in[11];
    const float* conv_b = (const float*)d_in[12];
    const float* Wo     = (const float*)d_in[13];
    const float* bo     = (const float*)d_in[14];

    // ws (bf16 buffers, 160.5 MiB total):
    unsigned short* ws    = (unsigned short*)d_ws;
    unsigned short* v16   = ws;              // (B,H,W,C)
    unsigned short* lepe16= v16 + NEL;       // (B,H,W,C)
    unsigned short* qr16  = lepe16 + NEL;    // (B,NH,H,W,KD)
    unsigned short* kr16  = qr16 + NEL;
    unsigned short* y16   = kr16 + NEL;      // (B,H,W,C)
    unsigned short* Wt16  = y16 + NEL;       // (768,256)
    unsigned short* Wot16 = Wt16 + 768 * 256;// (256,256)

    // d_out scratch: lower half = vv16 (bf16), upper half = x16 (bf16).
    // x16 is consumed by qkv_mfma (before vv16 is written); gemm_out_mfma
    // overwrites all of d_out at the end.
    unsigned short* vv16 = (unsigned short*)d_out;
    unsigned short* x16  = (unsigned short*)d_out + NEL;

    prep_x16<<<(int)(NEL / 2048), 256, 0, stream>>>(x, x16);
    trans_w<<<32, 256, 0, stream>>>(Wq, Wt16);
    trans_w<<<32, 256, 0, stream>>>(Wk, Wt16 + 256 * 256);
    trans_w<<<32, 256, 0, stream>>>(Wv, Wt16 + 512 * 256);
    trans_w<<<32, 256, 0, stream>>>(Wo, Wot16);

    qkv_mfma<<<dim3(M_TOT / 128, 6), 256, 0, stream>>>(
        x16, Wt16, bq, bk, bv, sin_t, cos_t, qr16, kr16, v16);

    conv_kernel<<<(int)(NEL / 256), 256, 0, stream>>>(v16, conv_w, conv_b, lepe16);

    attn_kernel<0><<<B * H * NH, 256, 0, stream>>>(qr16, kr16, v16, mask_w, nullptr, vv16);

    attn_kernel<1><<<B * W * NH, 256, 0, stream>>>(qr16, kr16, vv16, mask_h, lepe16, y16);

    gemm_out_mfma<<<dim3(M_TOT / 128, 2), 256, 0, stream>>>(y16, Wot16, bo, (float*)d_out);
}

// Round 5
// 451.070 us; speedup vs baseline: 2.4195x; 1.3392x over previous
//
#include <hip/hip_runtime.h>

typedef __attribute__((ext_vector_type(8))) short bf16x8;
typedef __attribute__((ext_vector_type(4))) float f32x4;

constexpr int B  = 16;
constexpr int H  = 64;
constexpr int W  = 64;
constexpr int C  = 256;
constexpr int NH = 8;
constexpr int KD = 32;
constexpr float SCALE = 0.17677669529663687f; // 32^-0.5
constexpr int M_TOT = B * H * W;              // 65536
constexpr size_t NEL = (size_t)B * H * W * C; // 16777216

__device__ __forceinline__ unsigned short f2bf(float f) {
    union { float f; unsigned int u; } x; x.f = f;
    unsigned int u = x.u;
    unsigned int r = (u + 0x7fffu + ((u >> 16) & 1u)) >> 16;
    return (unsigned short)r;
}
__device__ __forceinline__ float bf2f(unsigned short s) {
    union { unsigned int u; float f; } x; x.u = ((unsigned int)s) << 16; return x.f;
}
__device__ __forceinline__ float bf_lo(unsigned int u) {
    union { unsigned int u; float f; } x; x.u = u << 16; return x.f;
}
__device__ __forceinline__ float bf_hi(unsigned int u) {
    union { unsigned int u; float f; } x; x.u = u & 0xffff0000u; return x.f;
}
__device__ __forceinline__ unsigned int pack2(float a, float b) {
    return (unsigned int)f2bf(a) | ((unsigned int)f2bf(b) << 16);
}
// LDS chunk swizzle: row of 32 bf16 (64B) split into 4 16B chunks; XOR chunk id
// with bits 2-3 of row so ds_read_b128 column reads land on distinct bank pairs.
__device__ __forceinline__ int swz(int row, int kp8) {
    return row * 32 + (kp8 ^ (((row >> 2) & 3) << 3));
}

// ---------------------------------------------------------------------------
// prep: x fp32 -> bf16
// ---------------------------------------------------------------------------
__global__ __launch_bounds__(256) void prep_x16(const float* __restrict__ x,
                                                unsigned short* __restrict__ x16) {
    size_t i8 = ((size_t)blockIdx.x * 256 + threadIdx.x) * 8;
    float4 f0 = *(const float4*)(x + i8);
    float4 f1 = *(const float4*)(x + i8 + 4);
    uint4 o;
    o.x = pack2(f0.x, f0.y); o.y = pack2(f0.z, f0.w);
    o.z = pack2(f1.x, f1.y); o.w = pack2(f1.z, f1.w);
    *(uint4*)(x16 + i8) = o;
}

// ---------------------------------------------------------------------------
// prep: W (256k x 256n fp32, row-major k) -> Wt16[n][k] bf16 (n-major)
// ---------------------------------------------------------------------------
__global__ __launch_bounds__(256) void trans_w(const float* __restrict__ src,
                                               unsigned short* __restrict__ dst) {
    int tid = blockIdx.x * 256 + threadIdx.x;   // 0..8191
    int n = tid >> 5, k0 = (tid & 31) << 3;
    unsigned int p[4];
#pragma unroll
    for (int j = 0; j < 4; ++j) {
        float a  = src[(size_t)(k0 + 2 * j) * 256 + n];
        float b2 = src[(size_t)(k0 + 2 * j + 1) * 256 + n];
        p[j] = pack2(a, b2);
    }
    uint4 o = {p[0], p[1], p[2], p[3]};
    *(uint4*)(dst + (size_t)n * 256 + k0) = o;
}

// ---------------------------------------------------------------------------
// Kernel 1: fused QKV MFMA GEMM. x16(M,256)bf16 @ Wt16(768,256)^T.
// 128x128 tile, BK=32, 4 waves (each 64x64 = 4x4 16x16 frags).
// ---------------------------------------------------------------------------
__global__ __launch_bounds__(256) void qkv_mfma(
    const unsigned short* __restrict__ x16, const unsigned short* __restrict__ Wt16,
    const float* __restrict__ bq, const float* __restrict__ bk, const float* __restrict__ bv,
    const float* __restrict__ sin_t, const float* __restrict__ cos_t,
    unsigned short* __restrict__ qr, unsigned short* __restrict__ kr,
    unsigned short* __restrict__ v16)
{
    __shared__ __align__(16) short As[128 * 32];
    __shared__ __align__(16) short Bs[128 * 32];

    const int t = threadIdx.x;
    const int lane = t & 63, wid = t >> 6;
    const int wr = wid >> 1, wc = wid & 1;
    const int m0 = blockIdx.x * 128;
    const int n0 = blockIdx.y * 128;
    const int matid = blockIdx.y >> 1;

    f32x4 acc[4][4];
#pragma unroll
    for (int i = 0; i < 4; ++i)
#pragma unroll
        for (int j = 0; j < 4; ++j)
#pragma unroll
            for (int q = 0; q < 4; ++q) acc[i][j][q] = 0.f;

    const int row_s = t >> 2;            // 0..63
    const int kp_s  = (t & 3) << 3;      // 0,8,16,24

    for (int ks = 0; ks < 8; ++ks) {
        const int k0 = ks * 32;
        const unsigned short* ap = x16 + (size_t)(m0 + row_s) * 256 + k0 + kp_s;
        uint4 a0 = *(const uint4*)ap;
        uint4 a1 = *(const uint4*)(ap + 64 * 256);
        const unsigned short* bp = Wt16 + (size_t)(n0 + row_s) * 256 + k0 + kp_s;
        uint4 b0 = *(const uint4*)bp;
        uint4 b1 = *(const uint4*)(bp + 64 * 256);

        __syncthreads();
        *(uint4*)(&As[swz(row_s,      kp_s)]) = a0;
        *(uint4*)(&As[swz(row_s + 64, kp_s)]) = a1;
        *(uint4*)(&Bs[swz(row_s,      kp_s)]) = b0;
        *(uint4*)(&Bs[swz(row_s + 64, kp_s)]) = b1;
        __syncthreads();

        bf16x8 af[4], bf[4];
        const int rsel = lane & 15, kg8 = (lane >> 4) << 3;
#pragma unroll
        for (int i = 0; i < 4; ++i)
            af[i] = *(const bf16x8*)(&As[swz(wr * 64 + i * 16 + rsel, kg8)]);
#pragma unroll
        for (int j = 0; j < 4; ++j)
            bf[j] = *(const bf16x8*)(&Bs[swz(wc * 64 + j * 16 + rsel, kg8)]);
#pragma unroll
        for (int i = 0; i < 4; ++i)
#pragma unroll
            for (int j = 0; j < 4; ++j)
                acc[i][j] = __builtin_amdgcn_mfma_f32_16x16x32_bf16(af[i], bf[j], acc[i][j], 0, 0, 0);
    }

    // epilogue. C frag: col = lane&15, row = (lane>>4)*4 + r
    const int col_l = lane & 15, rowg = (lane >> 4) << 2;
    if (matid == 2) {
#pragma unroll
        for (int i = 0; i < 4; ++i)
#pragma unroll
            for (int j = 0; j < 4; ++j) {
                int nn = (n0 & 255) + wc * 64 + j * 16 + col_l;
                float bias = bv[nn];
#pragma unroll
                for (int r = 0; r < 4; ++r) {
                    int m = m0 + wr * 64 + i * 16 + rowg + r;
                    v16[(size_t)m * 256 + nn] = f2bf(acc[i][j][r] + bias);
                }
            }
    } else {
        const float sc = matid ? SCALE : 1.0f;
        const float* __restrict__ bias = matid ? bk : bq;
        unsigned short* __restrict__ dst = matid ? kr : qr;
        const int par = lane & 1;
#pragma unroll
        for (int i = 0; i < 4; ++i)
#pragma unroll
            for (int j = 0; j < 4; ++j) {
                int nn = (n0 & 255) + wc * 64 + j * 16 + col_l;
                int nh = nn >> 5, d = nn & 31;
                float bs = bias[nn];
#pragma unroll
                for (int r = 0; r < 4; ++r) {
                    int m = m0 + wr * 64 + i * 16 + rowg + r;
                    float val = (acc[i][j][r] + bs) * sc;
                    float p = __shfl_xor(val, 1);
                    int bb = m >> 12, hh = (m >> 6) & 63, ww = m & 63;
                    size_t ti = ((size_t)(hh << 6) + ww) * 32 + d;
                    float cs = cos_t[ti], sn = sin_t[ti];
                    float ov = par ? (val * cs + p * sn) : (val * cs - p * sn);
                    dst[((((size_t)bb * 8 + nh) * 64 + hh) * 64 + ww) * 32 + d] = f2bf(ov);
                }
            }
    }
}

// ---------------------------------------------------------------------------
// Kernel 2: 5x5 depthwise conv (lepe), bf16 in/out, 8 channels per thread
// ---------------------------------------------------------------------------
__global__ __launch_bounds__(256) void conv_kernel(
    const unsigned short* __restrict__ v, const float* __restrict__ cw,
    const float* __restrict__ cb, unsigned short* __restrict__ lepe)
{
    size_t tid = (size_t)blockIdx.x * 256 + threadIdx.x;  // 2M threads
    const int c8 = (int)(tid & 31) << 3;  // channel group of 8
    const int w  = (int)(tid >> 5) & 63;
    const int h  = (int)(tid >> 11) & 63;
    const int b  = (int)(tid >> 17);

    float acc[8];
    {
        float4 cb0 = *(const float4*)(cb + c8);
        float4 cb1 = *(const float4*)(cb + c8 + 4);
        acc[0] = cb0.x; acc[1] = cb0.y; acc[2] = cb0.z; acc[3] = cb0.w;
        acc[4] = cb1.x; acc[5] = cb1.y; acc[6] = cb1.z; acc[7] = cb1.w;
    }

    const unsigned short* __restrict__ vb = v + (size_t)b * 4096 * 256 + c8;
#pragma unroll
    for (int dy = 0; dy < 5; ++dy) {
        int yy = h + dy - 2;
        if (yy < 0 || yy >= 64) continue;
#pragma unroll
        for (int dx = 0; dx < 5; ++dx) {
            int xx = w + dx - 2;
            if (xx < 0 || xx >= 64) continue;
            uint4 rv = *(const uint4*)(vb + (size_t)(yy * 64 + xx) * 256);
            const float* wp = cw + (dy * 5 + dx) * 256 + c8;
            float4 w0 = *(const float4*)wp;
            float4 w1 = *(const float4*)(wp + 4);
            acc[0] += bf_lo(rv.x) * w0.x; acc[1] += bf_hi(rv.x) * w0.y;
            acc[2] += bf_lo(rv.y) * w0.z; acc[3] += bf_hi(rv.y) * w0.w;
            acc[4] += bf_lo(rv.z) * w1.x; acc[5] += bf_hi(rv.z) * w1.y;
            acc[6] += bf_lo(rv.w) * w1.z; acc[7] += bf_hi(rv.w) * w1.w;
        }
    }

    uint4 ov;
    ov.x = pack2(acc[0], acc[1]); ov.y = pack2(acc[2], acc[3]);
    ov.z = pack2(acc[4], acc[5]); ov.w = pack2(acc[6], acc[7]);
    *(uint4*)(lepe + tid * 8) = ov;
}

// ---------------------------------------------------------------------------
// Kernel 3/4: attention along one axis (all tensor I/O bf16, math fp32)
// ---------------------------------------------------------------------------
template <int AXIS>
__global__ __launch_bounds__(256) void attn_kernel(
    const unsigned short* __restrict__ qr, const unsigned short* __restrict__ kr,
    const unsigned short* __restrict__ vin, const float* __restrict__ mask,
    const unsigned short* __restrict__ addin, unsigned short* __restrict__ outp)
{
    __shared__ float qs[64][33], ks[64][33], vs[64][33];
    __shared__ float S[64][65];

    const int t   = threadIdx.x;
    const int bid = blockIdx.x;
    const int nh  = bid & 7;
    const int pos = (bid >> 3) & 63;
    const int b   = bid >> 9;

    size_t qbase, vbase;
    int qstride, vstride;
    if (AXIS == 0) {
        qbase   = ((size_t)(b * 8 + nh) * 64 + pos) * 2048;
        qstride = 32;
        vbase   = ((size_t)(b * 64 + pos) * 64) * 256 + nh * 32;
        vstride = 256;
    } else {
        qbase   = ((size_t)(b * 8 + nh) * 64) * 2048 + pos * 32;
        qstride = 2048;
        vbase   = ((size_t)b * 64 * 64) * 256 + pos * 256 + nh * 32;
        vstride = 16384;
    }

    {
        int row = t >> 2, c8 = (t & 3) * 8;
        uint4 rq = *(const uint4*)(qr + qbase + (size_t)row * qstride + c8);
        qs[row][c8 + 0] = bf_lo(rq.x); qs[row][c8 + 1] = bf_hi(rq.x);
        qs[row][c8 + 2] = bf_lo(rq.y); qs[row][c8 + 3] = bf_hi(rq.y);
        qs[row][c8 + 4] = bf_lo(rq.z); qs[row][c8 + 5] = bf_hi(rq.z);
        qs[row][c8 + 6] = bf_lo(rq.w); qs[row][c8 + 7] = bf_hi(rq.w);
        uint4 rk = *(const uint4*)(kr + qbase + (size_t)row * qstride + c8);
        ks[row][c8 + 0] = bf_lo(rk.x); ks[row][c8 + 1] = bf_hi(rk.x);
        ks[row][c8 + 2] = bf_lo(rk.y); ks[row][c8 + 3] = bf_hi(rk.y);
        ks[row][c8 + 4] = bf_lo(rk.z); ks[row][c8 + 5] = bf_hi(rk.z);
        ks[row][c8 + 6] = bf_lo(rk.w); ks[row][c8 + 7] = bf_hi(rk.w);
        uint4 rv = *(const uint4*)(vin + vbase + (size_t)row * vstride + c8);
        vs[row][c8 + 0] = bf_lo(rv.x); vs[row][c8 + 1] = bf_hi(rv.x);
        vs[row][c8 + 2] = bf_lo(rv.y); vs[row][c8 + 3] = bf_hi(rv.y);
        vs[row][c8 + 4] = bf_lo(rv.z); vs[row][c8 + 5] = bf_hi(rv.z);
        vs[row][c8 + 6] = bf_lo(rv.w); vs[row][c8 + 7] = bf_hi(rv.w);
    }
    __syncthreads();

    {
        const int tr = t >> 4, tc = t & 15;
        const float* __restrict__ mrow = mask + (size_t)nh * 4096;
        float acc[4][4] = {};
#pragma unroll
        for (int d = 0; d < 32; ++d) {
            float a[4], bb[4];
#pragma unroll
            for (int i = 0; i < 4; ++i) a[i] = qs[tr * 4 + i][d];
#pragma unroll
            for (int j = 0; j < 4; ++j) bb[j] = ks[tc * 4 + j][d];
#pragma unroll
            for (int i = 0; i < 4; ++i)
#pragma unroll
                for (int j = 0; j < 4; ++j) acc[i][j] += a[i] * bb[j];
        }
#pragma unroll
        for (int i = 0; i < 4; ++i)
#pragma unroll
            for (int j = 0; j < 4; ++j) {
                int r = tr * 4 + i, c = tc * 4 + j;
                S[r][c] = acc[i][j] + mrow[r * 64 + c];
            }
    }
    __syncthreads();

    {
        int r = t >> 2, c0 = (t & 3) * 16;
        float mx = -1e30f;
#pragma unroll
        for (int j = 0; j < 16; ++j) mx = fmaxf(mx, S[r][c0 + j]);
        mx = fmaxf(mx, __shfl_xor(mx, 1));
        mx = fmaxf(mx, __shfl_xor(mx, 2));
        float sum = 0.f;
        float ev[16];
#pragma unroll
        for (int j = 0; j < 16; ++j) { float e = __expf(S[r][c0 + j] - mx); ev[j] = e; sum += e; }
        sum += __shfl_xor(sum, 1);
        sum += __shfl_xor(sum, 2);
        float inv = 1.0f / sum;
#pragma unroll
        for (int j = 0; j < 16; ++j) S[r][c0 + j] = ev[j] * inv;
    }
    __syncthreads();

    {
        int r = t >> 2, d0 = (t & 3) * 8;
        float o[8] = {};
#pragma unroll 8
        for (int k = 0; k < 64; ++k) {
            float pv = S[r][k];
#pragma unroll
            for (int j = 0; j < 8; ++j) o[j] += pv * vs[k][d0 + j];
        }
        size_t oidx = vbase + (size_t)r * vstride + d0;
        if (AXIS == 1) {
            uint4 lv = *(const uint4*)(addin + oidx);
            o[0] += bf_lo(lv.x); o[1] += bf_hi(lv.x);
            o[2] += bf_lo(lv.y); o[3] += bf_hi(lv.y);
            o[4] += bf_lo(lv.z); o[5] += bf_hi(lv.z);
            o[6] += bf_lo(lv.w); o[7] += bf_hi(lv.w);
        }
        uint4 ov;
        ov.x = pack2(o[0], o[1]); ov.y = pack2(o[2], o[3]);
        ov.z = pack2(o[4], o[5]); ov.w = pack2(o[6], o[7]);
        *(uint4*)(outp + oidx) = ov;
    }
}

// ---------------------------------------------------------------------------
// Kernel 5: output MFMA GEMM: y16(M,256)bf16 @ Wot16(256,256)^T + bo -> fp32
// ---------------------------------------------------------------------------
__global__ __launch_bounds__(256) void gemm_out_mfma(
    const unsigned short* __restrict__ y16, const unsigned short* __restrict__ Wot16,
    const float* __restrict__ bo, float* __restrict__ out)
{
    __shared__ __align__(16) short As[128 * 32];
    __shared__ __align__(16) short Bs[128 * 32];

    const int t = threadIdx.x;
    const int lane = t & 63, wid = t >> 6;
    const int wr = wid >> 1, wc = wid & 1;
    const int m0 = blockIdx.x * 128;
    const int n0 = blockIdx.y * 128;

    f32x4 acc[4][4];
#pragma unroll
    for (int i = 0; i < 4; ++i)
#pragma unroll
        for (int j = 0; j < 4; ++j)
#pragma unroll
            for (int q = 0; q < 4; ++q) acc[i][j][q] = 0.f;

    const int row_s = t >> 2;
    const int kp_s  = (t & 3) << 3;

    for (int ks = 0; ks < 8; ++ks) {
        const int k0 = ks * 32;
        const unsigned short* ap = y16 + (size_t)(m0 + row_s) * 256 + k0 + kp_s;
        uint4 a0 = *(const uint4*)ap;
        uint4 a1 = *(const uint4*)(ap + 64 * 256);
        const unsigned short* bp = Wot16 + (size_t)(n0 + row_s) * 256 + k0 + kp_s;
        uint4 b0 = *(const uint4*)bp;
        uint4 b1 = *(const uint4*)(bp + 64 * 256);

        __syncthreads();
        *(uint4*)(&As[swz(row_s,      kp_s)]) = a0;
        *(uint4*)(&As[swz(row_s + 64, kp_s)]) = a1;
        *(uint4*)(&Bs[swz(row_s,      kp_s)]) = b0;
        *(uint4*)(&Bs[swz(row_s + 64, kp_s)]) = b1;
        __syncthreads();

        bf16x8 af[4], bf[4];
        const int rsel = lane & 15, kg8 = (lane >> 4) << 3;
#pragma unroll
        for (int i = 0; i < 4; ++i)
            af[i] = *(const bf16x8*)(&As[swz(wr * 64 + i * 16 + rsel, kg8)]);
#pragma unroll
        for (int j = 0; j < 4; ++j)
            bf[j] = *(const bf16x8*)(&Bs[swz(wc * 64 + j * 16 + rsel, kg8)]);
#pragma unroll
        for (int i = 0; i < 4; ++i)
#pragma unroll
            for (int j = 0; j < 4; ++j)
                acc[i][j] = __builtin_amdgcn_mfma_f32_16x16x32_bf16(af[i], bf[j], acc[i][j], 0, 0, 0);
    }

    const int col_l = lane & 15, rowg = (lane >> 4) << 2;
#pragma unroll
    for (int i = 0; i < 4; ++i)
#pragma unroll
        for (int j = 0; j < 4; ++j) {
            int nn = n0 + wc * 64 + j * 16 + col_l;
            float bias = bo[nn];
#pragma unroll
            for (int r = 0; r < 4; ++r) {
                int m = m0 + wr * 64 + i * 16 + rowg + r;
                out[(size_t)m * 256 + nn] = acc[i][j][r] + bias;
            }
        }
}

// ---------------------------------------------------------------------------
extern "C" void kernel_launch(void* const* d_in, const int* in_sizes, int n_in,
                              void* d_out, int out_size, void* d_ws, size_t ws_size,
                              hipStream_t stream) {
    const float* x      = (const float*)d_in[0];
    const float* sin_t  = (const float*)d_in[1];
    const float* cos_t  = (const float*)d_in[2];
    const float* mask_h = (const float*)d_in[3];
    const float* mask_w = (const float*)d_in[4];
    const float* Wq     = (const float*)d_in[5];
    const float* bq     = (const float*)d_in[6];
    const float* Wk     = (const float*)d_in[7];
    const float* bk     = (const float*)d_in[8];
    const float* Wv     = (const float*)d_in[9];
    const float* bv     = (const float*)d_in[10];
    const float* conv_w = (const float*)d_in[11];
    const float* conv_b = (const float*)d_in[12];
    const float* Wo     = (const float*)d_in[13];
    const float* bo     = (const float*)d_in[14];

    // ws (bf16 buffers, 160.5 MiB total)
    unsigned short* ws    = (unsigned short*)d_ws;
    unsigned short* v16   = ws;              // (B,H,W,C)
    unsigned short* lepe16= v16 + NEL;       // (B,H,W,C)
    unsigned short* qr16  = lepe16 + NEL;    // (B,NH,H,W,KD)
    unsigned short* kr16  = qr16 + NEL;
    unsigned short* y16   = kr16 + NEL;      // (B,H,W,C)
    unsigned short* Wt16  = y16 + NEL;       // (768,256)
    unsigned short* Wot16 = Wt16 + 768 * 256;// (256,256)

    // d_out scratch: lower half = vv16 (bf16), upper half = x16 (bf16).
    unsigned short* vv16 = (unsigned short*)d_out;
    unsigned short* x16  = (unsigned short*)d_out + NEL;

    prep_x16<<<(int)(NEL / 2048), 256, 0, stream>>>(x, x16);
    trans_w<<<32, 256, 0, stream>>>(Wq, Wt16);
    trans_w<<<32, 256, 0, stream>>>(Wk, Wt16 + 256 * 256);
    trans_w<<<32, 256, 0, stream>>>(Wv, Wt16 + 512 * 256);
    trans_w<<<32, 256, 0, stream>>>(Wo, Wot16);

    qkv_mfma<<<dim3(M_TOT / 128, 6), 256, 0, stream>>>(
        x16, Wt16, bq, bk, bv, sin_t, cos_t, qr16, kr16, v16);

    conv_kernel<<<(int)(NEL / 2048), 256, 0, stream>>>(v16, conv_w, conv_b, lepe16);

    attn_kernel<0><<<B * H * NH, 256, 0, stream>>>(qr16, kr16, v16, mask_w, nullptr, vv16);

    attn_kernel<1><<<B * W * NH, 256, 0, stream>>>(qr16, kr16, vv16, mask_h, lepe16, y16);

    gemm_out_mfma<<<dim3(M_TOT / 128, 2), 256, 0, stream>>>(y16, Wot16, bo, (float*)d_out);
}

// Round 6
// 260.568 us; speedup vs baseline: 4.1884x; 1.7311x over previous
//
#include <hip/hip_runtime.h>

typedef __attribute__((ext_vector_type(8))) short bf16x8;
typedef __attribute__((ext_vector_type(4))) float f32x4;

constexpr int B  = 16;
constexpr int H  = 64;
constexpr int W  = 64;
constexpr int C  = 256;
constexpr int NH = 8;
constexpr int KD = 32;
constexpr float SCALE = 0.17677669529663687f; // 32^-0.5
constexpr int M_TOT = B * H * W;              // 65536
constexpr size_t NEL = (size_t)B * H * W * C; // 16777216

__device__ __forceinline__ unsigned short f2bf(float f) {
    union { float f; unsigned int u; } x; x.f = f;
    unsigned int u = x.u;
    unsigned int r = (u + 0x7fffu + ((u >> 16) & 1u)) >> 16;
    return (unsigned short)r;
}
__device__ __forceinline__ float bf2f(unsigned short s) {
    union { unsigned int u; float f; } x; x.u = ((unsigned int)s) << 16; return x.f;
}
__device__ __forceinline__ float bf_lo(unsigned int u) {
    union { unsigned int u; float f; } x; x.u = u << 16; return x.f;
}
__device__ __forceinline__ float bf_hi(unsigned int u) {
    union { unsigned int u; float f; } x; x.u = u & 0xffff0000u; return x.f;
}
__device__ __forceinline__ unsigned int pack2(float a, float b) {
    return (unsigned int)f2bf(a) | ((unsigned int)f2bf(b) << 16);
}
// LDS chunk swizzle for the GEMM kernels (64B rows of 32 bf16)
__device__ __forceinline__ int swz(int row, int kp8) {
    return row * 32 + (kp8 ^ (((row >> 2) & 3) << 3));
}

// ---------------------------------------------------------------------------
// prep: x fp32 -> bf16
// ---------------------------------------------------------------------------
__global__ __launch_bounds__(256) void prep_x16(const float* __restrict__ x,
                                                unsigned short* __restrict__ x16) {
    size_t i8 = ((size_t)blockIdx.x * 256 + threadIdx.x) * 8;
    float4 f0 = *(const float4*)(x + i8);
    float4 f1 = *(const float4*)(x + i8 + 4);
    uint4 o;
    o.x = pack2(f0.x, f0.y); o.y = pack2(f0.z, f0.w);
    o.z = pack2(f1.x, f1.y); o.w = pack2(f1.z, f1.w);
    *(uint4*)(x16 + i8) = o;
}

// ---------------------------------------------------------------------------
// prep: W (256k x 256n fp32, row-major k) -> Wt16[n][k] bf16 (n-major)
// ---------------------------------------------------------------------------
__global__ __launch_bounds__(256) void trans_w(const float* __restrict__ src,
                                               unsigned short* __restrict__ dst) {
    int tid = blockIdx.x * 256 + threadIdx.x;   // 0..8191
    int n = tid >> 5, k0 = (tid & 31) << 3;
    unsigned int p[4];
#pragma unroll
    for (int j = 0; j < 4; ++j) {
        float a  = src[(size_t)(k0 + 2 * j) * 256 + n];
        float b2 = src[(size_t)(k0 + 2 * j + 1) * 256 + n];
        p[j] = pack2(a, b2);
    }
    uint4 o = {p[0], p[1], p[2], p[3]};
    *(uint4*)(dst + (size_t)n * 256 + k0) = o;
}

// ---------------------------------------------------------------------------
// Kernel 1: fused QKV MFMA GEMM. x16(M,256)bf16 @ Wt16(768,256)^T.
// ---------------------------------------------------------------------------
__global__ __launch_bounds__(256) void qkv_mfma(
    const unsigned short* __restrict__ x16, const unsigned short* __restrict__ Wt16,
    const float* __restrict__ bq, const float* __restrict__ bk, const float* __restrict__ bv,
    const float* __restrict__ sin_t, const float* __restrict__ cos_t,
    unsigned short* __restrict__ qr, unsigned short* __restrict__ kr,
    unsigned short* __restrict__ v16)
{
    __shared__ __align__(16) short As[128 * 32];
    __shared__ __align__(16) short Bs[128 * 32];

    const int t = threadIdx.x;
    const int lane = t & 63, wid = t >> 6;
    const int wr = wid >> 1, wc = wid & 1;
    const int m0 = blockIdx.x * 128;
    const int n0 = blockIdx.y * 128;
    const int matid = blockIdx.y >> 1;

    f32x4 acc[4][4];
#pragma unroll
    for (int i = 0; i < 4; ++i)
#pragma unroll
        for (int j = 0; j < 4; ++j)
#pragma unroll
            for (int q = 0; q < 4; ++q) acc[i][j][q] = 0.f;

    const int row_s = t >> 2;            // 0..63
    const int kp_s  = (t & 3) << 3;      // 0,8,16,24

    for (int ks = 0; ks < 8; ++ks) {
        const int k0 = ks * 32;
        const unsigned short* ap = x16 + (size_t)(m0 + row_s) * 256 + k0 + kp_s;
        uint4 a0 = *(const uint4*)ap;
        uint4 a1 = *(const uint4*)(ap + 64 * 256);
        const unsigned short* bp = Wt16 + (size_t)(n0 + row_s) * 256 + k0 + kp_s;
        uint4 b0 = *(const uint4*)bp;
        uint4 b1 = *(const uint4*)(bp + 64 * 256);

        __syncthreads();
        *(uint4*)(&As[swz(row_s,      kp_s)]) = a0;
        *(uint4*)(&As[swz(row_s + 64, kp_s)]) = a1;
        *(uint4*)(&Bs[swz(row_s,      kp_s)]) = b0;
        *(uint4*)(&Bs[swz(row_s + 64, kp_s)]) = b1;
        __syncthreads();

        bf16x8 af[4], bf[4];
        const int rsel = lane & 15, kg8 = (lane >> 4) << 3;
#pragma unroll
        for (int i = 0; i < 4; ++i)
            af[i] = *(const bf16x8*)(&As[swz(wr * 64 + i * 16 + rsel, kg8)]);
#pragma unroll
        for (int j = 0; j < 4; ++j)
            bf[j] = *(const bf16x8*)(&Bs[swz(wc * 64 + j * 16 + rsel, kg8)]);
#pragma unroll
        for (int i = 0; i < 4; ++i)
#pragma unroll
            for (int j = 0; j < 4; ++j)
                acc[i][j] = __builtin_amdgcn_mfma_f32_16x16x32_bf16(af[i], bf[j], acc[i][j], 0, 0, 0);
    }

    // epilogue. C frag: col = lane&15, row = (lane>>4)*4 + r
    const int col_l = lane & 15, rowg = (lane >> 4) << 2;
    if (matid == 2) {
#pragma unroll
        for (int i = 0; i < 4; ++i)
#pragma unroll
            for (int j = 0; j < 4; ++j) {
                int nn = (n0 & 255) + wc * 64 + j * 16 + col_l;
                float bias = bv[nn];
#pragma unroll
                for (int r = 0; r < 4; ++r) {
                    int m = m0 + wr * 64 + i * 16 + rowg + r;
                    v16[(size_t)m * 256 + nn] = f2bf(acc[i][j][r] + bias);
                }
            }
    } else {
        const float sc = matid ? SCALE : 1.0f;
        const float* __restrict__ bias = matid ? bk : bq;
        unsigned short* __restrict__ dst = matid ? kr : qr;
        const int par = lane & 1;
#pragma unroll
        for (int i = 0; i < 4; ++i)
#pragma unroll
            for (int j = 0; j < 4; ++j) {
                int nn = (n0 & 255) + wc * 64 + j * 16 + col_l;
                int nh = nn >> 5, d = nn & 31;
                float bs = bias[nn];
#pragma unroll
                for (int r = 0; r < 4; ++r) {
                    int m = m0 + wr * 64 + i * 16 + rowg + r;
                    float val = (acc[i][j][r] + bs) * sc;
                    float p = __shfl_xor(val, 1);
                    int bb = m >> 12, hh = (m >> 6) & 63, ww = m & 63;
                    size_t ti = ((size_t)(hh << 6) + ww) * 32 + d;
                    float cs = cos_t[ti], sn = sin_t[ti];
                    float ov = par ? (val * cs + p * sn) : (val * cs - p * sn);
                    dst[((((size_t)bb * 8 + nh) * 64 + hh) * 64 + ww) * 32 + d] = f2bf(ov);
                }
            }
    }
}

// ---------------------------------------------------------------------------
// Kernel 2: 5x5 depthwise conv (lepe), bf16 in/out, 8 channels per thread
// ---------------------------------------------------------------------------
__global__ __launch_bounds__(256) void conv_kernel(
    const unsigned short* __restrict__ v, const float* __restrict__ cw,
    const float* __restrict__ cb, unsigned short* __restrict__ lepe)
{
    size_t tid = (size_t)blockIdx.x * 256 + threadIdx.x;  // 2M threads
    const int c8 = (int)(tid & 31) << 3;  // channel group of 8
    const int w  = (int)(tid >> 5) & 63;
    const int h  = (int)(tid >> 11) & 63;
    const int b  = (int)(tid >> 17);

    float acc[8];
    {
        float4 cb0 = *(const float4*)(cb + c8);
        float4 cb1 = *(const float4*)(cb + c8 + 4);
        acc[0] = cb0.x; acc[1] = cb0.y; acc[2] = cb0.z; acc[3] = cb0.w;
        acc[4] = cb1.x; acc[5] = cb1.y; acc[6] = cb1.z; acc[7] = cb1.w;
    }

    const unsigned short* __restrict__ vb = v + (size_t)b * 4096 * 256 + c8;
#pragma unroll
    for (int dy = 0; dy < 5; ++dy) {
        int yy = h + dy - 2;
        if (yy < 0 || yy >= 64) continue;
#pragma unroll
        for (int dx = 0; dx < 5; ++dx) {
            int xx = w + dx - 2;
            if (xx < 0 || xx >= 64) continue;
            uint4 rv = *(const uint4*)(vb + (size_t)(yy * 64 + xx) * 256);
            const float* wp = cw + (dy * 5 + dx) * 256 + c8;
            float4 w0 = *(const float4*)wp;
            float4 w1 = *(const float4*)(wp + 4);
            acc[0] += bf_lo(rv.x) * w0.x; acc[1] += bf_hi(rv.x) * w0.y;
            acc[2] += bf_lo(rv.y) * w0.z; acc[3] += bf_hi(rv.y) * w0.w;
            acc[4] += bf_lo(rv.z) * w1.x; acc[5] += bf_hi(rv.z) * w1.y;
            acc[6] += bf_lo(rv.w) * w1.z; acc[7] += bf_hi(rv.w) * w1.w;
        }
    }

    uint4 ov;
    ov.x = pack2(acc[0], acc[1]); ov.y = pack2(acc[2], acc[3]);
    ov.z = pack2(acc[4], acc[5]); ov.w = pack2(acc[6], acc[7]);
    *(uint4*)(lepe + tid * 8) = ov;
}

// ---------------------------------------------------------------------------
// Kernel 3/4: MFMA attention along one axis. One block per (b,pos,nh).
// 4 waves; wave w owns S/P/out rows w*16..w*16+15.
//   QK^T: S(16x64) = q(16x32) . k(64x32)^T  -> 4 MFMA
//   softmax in-register (cols on lane&15 + frag j; shfl_xor 1/2/4/8)
//   PV:  out(16x32) = P(16x64) . v(64x32)   -> 4 MFMA (vt = v^T in LDS)
// ---------------------------------------------------------------------------
template <int AXIS>
__global__ __launch_bounds__(256) void attn_mfma(
    const unsigned short* __restrict__ qr, const unsigned short* __restrict__ kr,
    const unsigned short* __restrict__ vin, const float* __restrict__ mask,
    const unsigned short* __restrict__ addin, unsigned short* __restrict__ outp)
{
    __shared__ __align__(16) short qs[64 * 40];  // [64][40] pad->free reads
    __shared__ __align__(16) short ks[64 * 40];
    __shared__ __align__(16) short vt[32 * 72];  // [d=32][k=64 +pad]
    __shared__ __align__(16) short P [64 * 72];  // [64][64 +pad]

    const int t    = threadIdx.x;
    const int lane = t & 63, wv = t >> 6;
    const int bid  = blockIdx.x;
    const int nh   = bid & 7;
    const int pos  = (bid >> 3) & 63;
    const int b    = bid >> 9;

    size_t qbase, vbase;
    int qstride, vstride;
    if (AXIS == 0) {
        qbase   = ((size_t)(b * 8 + nh) * 64 + pos) * 2048;
        qstride = 32;
        vbase   = ((size_t)(b * 64 + pos) * 64) * 256 + nh * 32;
        vstride = 256;
    } else {
        qbase   = ((size_t)(b * 8 + nh) * 64) * 2048 + pos * 32;
        qstride = 2048;
        vbase   = ((size_t)b * 64 * 64) * 256 + pos * 256 + nh * 32;
        vstride = 16384;
    }

    // ---- stage q,k row-major; v transposed ----
    {
        int row = t >> 2, c8 = (t & 3) << 3;
        uint4 rq = *(const uint4*)(qr + qbase + (size_t)row * qstride + c8);
        *(uint4*)(&qs[row * 40 + c8]) = rq;
        uint4 rk = *(const uint4*)(kr + qbase + (size_t)row * qstride + c8);
        *(uint4*)(&ks[row * 40 + c8]) = rk;
        uint4 rv = *(const uint4*)(vin + vbase + (size_t)row * vstride + c8);
        const unsigned short* pv = (const unsigned short*)&rv;
#pragma unroll
        for (int j = 0; j < 8; ++j) vt[(c8 + j) * 72 + row] = pv[j];
    }
    __syncthreads();

    const int rsel = lane & 15;
    const int kg   = (lane >> 4) << 3;      // k-offset 0,8,16,24
    const int rowg = (lane >> 4) << 2;      // C-frag row group

    // ---- QK^T ----
    bf16x8 aq = *(const bf16x8*)(&qs[(wv * 16 + rsel) * 40 + kg]);
    f32x4 s[4];
#pragma unroll
    for (int j = 0; j < 4; ++j) {
        f32x4 z = {0.f, 0.f, 0.f, 0.f};
        bf16x8 bk8 = *(const bf16x8*)(&ks[(j * 16 + rsel) * 40 + kg]);
        s[j] = __builtin_amdgcn_mfma_f32_16x16x32_bf16(aq, bk8, z, 0, 0, 0);
    }

    // ---- mask + softmax in-register; write P (bf16) ----
    const float* __restrict__ mrow = mask + (size_t)nh * 4096;
#pragma unroll
    for (int r = 0; r < 4; ++r) {
        const int grow = wv * 16 + rowg + r;
#pragma unroll
        for (int j = 0; j < 4; ++j)
            s[j][r] += mrow[grow * 64 + j * 16 + rsel];
        float mx = fmaxf(fmaxf(s[0][r], s[1][r]), fmaxf(s[2][r], s[3][r]));
        mx = fmaxf(mx, __shfl_xor(mx, 1));
        mx = fmaxf(mx, __shfl_xor(mx, 2));
        mx = fmaxf(mx, __shfl_xor(mx, 4));
        mx = fmaxf(mx, __shfl_xor(mx, 8));
        float e0 = __expf(s[0][r] - mx), e1 = __expf(s[1][r] - mx);
        float e2 = __expf(s[2][r] - mx), e3 = __expf(s[3][r] - mx);
        float sum = e0 + e1 + e2 + e3;
        sum += __shfl_xor(sum, 1);
        sum += __shfl_xor(sum, 2);
        sum += __shfl_xor(sum, 4);
        sum += __shfl_xor(sum, 8);
        float inv = 1.0f / sum;
        P[grow * 72 +      rsel] = f2bf(e0 * inv);
        P[grow * 72 + 16 + rsel] = f2bf(e1 * inv);
        P[grow * 72 + 32 + rsel] = f2bf(e2 * inv);
        P[grow * 72 + 48 + rsel] = f2bf(e3 * inv);
    }
    __syncthreads();

    // ---- PV ----
    f32x4 o[2];
#pragma unroll
    for (int n = 0; n < 2; ++n)
#pragma unroll
        for (int q = 0; q < 4; ++q) o[n][q] = 0.f;
#pragma unroll
    for (int kk = 0; kk < 2; ++kk) {
        bf16x8 ap = *(const bf16x8*)(&P[(wv * 16 + rsel) * 72 + kk * 32 + kg]);
#pragma unroll
        for (int n = 0; n < 2; ++n) {
            bf16x8 bv8 = *(const bf16x8*)(&vt[(n * 16 + rsel) * 72 + kk * 32 + kg]);
            o[n] = __builtin_amdgcn_mfma_f32_16x16x32_bf16(ap, bv8, o[n], 0, 0, 0);
        }
    }

    // ---- epilogue ----
#pragma unroll
    for (int n = 0; n < 2; ++n)
#pragma unroll
        for (int r = 0; r < 4; ++r) {
            const int grow = wv * 16 + rowg + r;
            size_t oidx = vbase + (size_t)grow * vstride + n * 16 + rsel;
            float val = o[n][r];
            if (AXIS == 1) val += bf2f(addin[oidx]);
            outp[oidx] = f2bf(val);
        }
}

// ---------------------------------------------------------------------------
// Kernel 5: output MFMA GEMM: y16(M,256)bf16 @ Wot16(256,256)^T + bo -> fp32
// ---------------------------------------------------------------------------
__global__ __launch_bounds__(256) void gemm_out_mfma(
    const unsigned short* __restrict__ y16, const unsigned short* __restrict__ Wot16,
    const float* __restrict__ bo, float* __restrict__ out)
{
    __shared__ __align__(16) short As[128 * 32];
    __shared__ __align__(16) short Bs[128 * 32];

    const int t = threadIdx.x;
    const int lane = t & 63, wid = t >> 6;
    const int wr = wid >> 1, wc = wid & 1;
    const int m0 = blockIdx.x * 128;
    const int n0 = blockIdx.y * 128;

    f32x4 acc[4][4];
#pragma unroll
    for (int i = 0; i < 4; ++i)
#pragma unroll
        for (int j = 0; j < 4; ++j)
#pragma unroll
            for (int q = 0; q < 4; ++q) acc[i][j][q] = 0.f;

    const int row_s = t >> 2;
    const int kp_s  = (t & 3) << 3;

    for (int ks = 0; ks < 8; ++ks) {
        const int k0 = ks * 32;
        const unsigned short* ap = y16 + (size_t)(m0 + row_s) * 256 + k0 + kp_s;
        uint4 a0 = *(const uint4*)ap;
        uint4 a1 = *(const uint4*)(ap + 64 * 256);
        const unsigned short* bp = Wot16 + (size_t)(n0 + row_s) * 256 + k0 + kp_s;
        uint4 b0 = *(const uint4*)bp;
        uint4 b1 = *(const uint4*)(bp + 64 * 256);

        __syncthreads();
        *(uint4*)(&As[swz(row_s,      kp_s)]) = a0;
        *(uint4*)(&As[swz(row_s + 64, kp_s)]) = a1;
        *(uint4*)(&Bs[swz(row_s,      kp_s)]) = b0;
        *(uint4*)(&Bs[swz(row_s + 64, kp_s)]) = b1;
        __syncthreads();

        bf16x8 af[4], bf[4];
        const int rsel = lane & 15, kg8 = (lane >> 4) << 3;
#pragma unroll
        for (int i = 0; i < 4; ++i)
            af[i] = *(const bf16x8*)(&As[swz(wr * 64 + i * 16 + rsel, kg8)]);
#pragma unroll
        for (int j = 0; j < 4; ++j)
            bf[j] = *(const bf16x8*)(&Bs[swz(wc * 64 + j * 16 + rsel, kg8)]);
#pragma unroll
        for (int i = 0; i < 4; ++i)
#pragma unroll
            for (int j = 0; j < 4; ++j)
                acc[i][j] = __builtin_amdgcn_mfma_f32_16x16x32_bf16(af[i], bf[j], acc[i][j], 0, 0, 0);
    }

    const int col_l = lane & 15, rowg = (lane >> 4) << 2;
#pragma unroll
    for (int i = 0; i < 4; ++i)
#pragma unroll
        for (int j = 0; j < 4; ++j) {
            int nn = n0 + wc * 64 + j * 16 + col_l;
            float bias = bo[nn];
#pragma unroll
            for (int r = 0; r < 4; ++r) {
                int m = m0 + wr * 64 + i * 16 + rowg + r;
                out[(size_t)m * 256 + nn] = acc[i][j][r] + bias;
            }
        }
}

// ---------------------------------------------------------------------------
extern "C" void kernel_launch(void* const* d_in, const int* in_sizes, int n_in,
                              void* d_out, int out_size, void* d_ws, size_t ws_size,
                              hipStream_t stream) {
    const float* x      = (const float*)d_in[0];
    const float* sin_t  = (const float*)d_in[1];
    const float* cos_t  = (const float*)d_in[2];
    const float* mask_h = (const float*)d_in[3];
    const float* mask_w = (const float*)d_in[4];
    const float* Wq     = (const float*)d_in[5];
    const float* bq     = (const float*)d_in[6];
    const float* Wk     = (const float*)d_in[7];
    const float* bk     = (const float*)d_in[8];
    const float* Wv     = (const float*)d_in[9];
    const float* bv     = (const float*)d_in[10];
    const float* conv_w = (const float*)d_in[11];
    const float* conv_b = (const float*)d_in[12];
    const float* Wo     = (const float*)d_in[13];
    const float* bo     = (const float*)d_in[14];

    // ws (bf16 buffers, 160.5 MiB total)
    unsigned short* ws    = (unsigned short*)d_ws;
    unsigned short* v16   = ws;              // (B,H,W,C)
    unsigned short* lepe16= v16 + NEL;       // (B,H,W,C)
    unsigned short* qr16  = lepe16 + NEL;    // (B,NH,H,W,KD)
    unsigned short* kr16  = qr16 + NEL;
    unsigned short* y16   = kr16 + NEL;      // (B,H,W,C)
    unsigned short* Wt16  = y16 + NEL;       // (768,256)
    unsigned short* Wot16 = Wt16 + 768 * 256;// (256,256)

    // d_out scratch: lower half = vv16 (bf16), upper half = x16 (bf16).
    unsigned short* vv16 = (unsigned short*)d_out;
    unsigned short* x16  = (unsigned short*)d_out + NEL;

    prep_x16<<<(int)(NEL / 2048), 256, 0, stream>>>(x, x16);
    trans_w<<<32, 256, 0, stream>>>(Wq, Wt16);
    trans_w<<<32, 256, 0, stream>>>(Wk, Wt16 + 256 * 256);
    trans_w<<<32, 256, 0, stream>>>(Wv, Wt16 + 512 * 256);
    trans_w<<<32, 256, 0, stream>>>(Wo, Wot16);

    qkv_mfma<<<dim3(M_TOT / 128, 6), 256, 0, stream>>>(
        x16, Wt16, bq, bk, bv, sin_t, cos_t, qr16, kr16, v16);

    conv_kernel<<<(int)(NEL / 2048), 256, 0, stream>>>(v16, conv_w, conv_b, lepe16);

    attn_mfma<0><<<B * H * NH, 256, 0, stream>>>(qr16, kr16, v16, mask_w, nullptr, vv16);

    attn_mfma<1><<<B * W * NH, 256, 0, stream>>>(qr16, kr16, vv16, mask_h, lepe16, y16);

    gemm_out_mfma<<<dim3(M_TOT / 128, 2), 256, 0, stream>>>(y16, Wot16, bo, (float*)d_out);
}